// Round 1
// baseline (14558.688 us; speedup 1.0000x reference)
//
#include <hip/hip_runtime.h>
#include <math.h>

#define N 8192
#define D 512
#define D4 (D / 4)      // 128 float4 per row
#define KSEL 5
#define TI 32           // rows per block in simtopk
#define JLT 16          // j-lane threads per row
#define BLK (TI * JLT)  // 512 threads
#define TEMP_INV 10.0f  // 1 / 0.1

// ---------------- Kernel 1: L2 row normalize -----------------------------
__global__ __launch_bounds__(64) void rownorm_kernel(const float* __restrict__ X,
                                                     float* __restrict__ Xn) {
    const int row = blockIdx.x;
    const int t = threadIdx.x;  // 0..63, one wave
    const float4* xr = (const float4*)(X + (size_t)row * D);
    float4 a = xr[t];
    float4 b = xr[t + 64];
    float ss = a.x * a.x + a.y * a.y + a.z * a.z + a.w * a.w +
               b.x * b.x + b.y * b.y + b.z * b.z + b.w * b.w;
#pragma unroll
    for (int off = 32; off > 0; off >>= 1) ss += __shfl_xor(ss, off, 64);
    const float inv = 1.0f / fmaxf(sqrtf(ss), 1e-12f);
    a.x *= inv; a.y *= inv; a.z *= inv; a.w *= inv;
    b.x *= inv; b.y *= inv; b.z *= inv; b.w *= inv;
    float4* o = (float4*)(Xn + (size_t)row * D);
    o[t] = a;
    o[t + 64] = b;
}

// ---------------- Kernel 2: fused sim + top-5 + softmax ------------------
// Block: 512 threads = 32 rows x 16 j-lanes. Rows staged in 64 KB LDS with
// per-row float4-slot rotation ((k4+r)&127) so a wave's 4 distinct r-groups
// hit disjoint bank quads (conflict-free ds_read_b128, no padding needed).
__global__ __launch_bounds__(BLK) void simtopk_kernel(const float* __restrict__ Xn,
                                                      float* __restrict__ topW,
                                                      int* __restrict__ topI) {
    __shared__ float xI[TI * D];  // exactly 64 KB
    float4* xI4 = (float4*)xI;
    const int tid = threadIdx.x;
    const int i0 = blockIdx.x * TI;

    // Stage 32 rows (coalesced float4), swizzled slots.
    for (int e = tid; e < TI * D4; e += BLK) {
        const int r = e >> 7;       // e / 128
        const int k4 = e & (D4 - 1);
        float4 v = ((const float4*)(Xn + (size_t)(i0 + r) * D))[k4];
        xI4[r * D4 + ((k4 + r) & (D4 - 1))] = v;
    }
    __syncthreads();

    const int r = tid >> 4;    // 0..31 row within tile
    const int jl = tid & 15;   // 0..15 j-lane
    const float4* xr4 = xI4 + r * D4;

    float tv0 = -1e30f, tv1 = -1e30f, tv2 = -1e30f, tv3 = -1e30f, tv4 = -1e30f;
    int ti0 = -1, ti1 = -1, ti2 = -1, ti3 = -1, ti4 = -1;

    auto ins = [&](float v, int j) {
        if (v > tv4) {
            if (v > tv3) {
                tv4 = tv3; ti4 = ti3;
                if (v > tv2) {
                    tv3 = tv2; ti3 = ti2;
                    if (v > tv1) {
                        tv2 = tv1; ti2 = ti1;
                        if (v > tv0) {
                            tv1 = tv0; ti1 = ti0; tv0 = v; ti0 = j;
                        } else { tv1 = v; ti1 = j; }
                    } else { tv2 = v; ti2 = j; }
                } else { tv3 = v; ti3 = j; }
            } else { tv4 = v; ti4 = j; }
        }
    };

    for (int j0 = 0; j0 < N; j0 += JLT * 4) {  // 4 j's per thread per pass
        const int ja = j0 + jl;
        const float4* pa = (const float4*)(Xn + (size_t)ja * D);
        const float4* pb = pa + (size_t)JLT * D4;
        const float4* pc = pb + (size_t)JLT * D4;
        const float4* pd = pc + (size_t)JLT * D4;
        float da = 0.f, db = 0.f, dc = 0.f, dd = 0.f;
#pragma unroll 4
        for (int k4 = 0; k4 < D4; ++k4) {
            const float4 a = xr4[(k4 + r) & (D4 - 1)];
            const float4 va = pa[k4];
            const float4 vb = pb[k4];
            const float4 vc = pc[k4];
            const float4 vd = pd[k4];
            da += a.x * va.x + a.y * va.y + a.z * va.z + a.w * va.w;
            db += a.x * vb.x + a.y * vb.y + a.z * vb.z + a.w * vb.w;
            dc += a.x * vc.x + a.y * vc.y + a.z * vc.z + a.w * vc.w;
            dd += a.x * vd.x + a.y * vd.y + a.z * vd.z + a.w * vd.w;
        }
        // ascending j order preserves lax.top_k's lower-index tie-break
        ins(da, ja);
        ins(db, ja + JLT);
        ins(dc, ja + 2 * JLT);
        ins(dd, ja + 3 * JLT);
    }

    // Reuse xI LDS for candidate merge (all reads of xI are done).
    __syncthreads();
    float* cv = xI;                                  // TI*JLT*KSEL = 2560 floats
    int* ci = (int*)(xI + TI * JLT * KSEL);          // another 2560 ints
    const int cb = (r * JLT + jl) * KSEL;
    cv[cb + 0] = tv0; ci[cb + 0] = ti0;
    cv[cb + 1] = tv1; ci[cb + 1] = ti1;
    cv[cb + 2] = tv2; ci[cb + 2] = ti2;
    cv[cb + 3] = tv3; ci[cb + 3] = ti3;
    cv[cb + 4] = tv4; ci[cb + 4] = ti4;
    __syncthreads();

    if (jl == 0) {
        // Merge 80 candidates for row r: repeated argmax with
        // (value desc, index asc) lexicographic order, excluding prior picks
        // by "strictly less than previous pick" in that order.
        const float* rv = cv + r * JLT * KSEL;
        const int* ri = ci + r * JLT * KSEL;
        float bw[KSEL];
        int bi[KSEL];
        float pv = 1e38f;
        int pi = -1;
#pragma unroll
        for (int s = 0; s < KSEL; ++s) {
            float best = -1e38f;
            int bidx = 0x7fffffff;
            for (int c = 0; c < JLT * KSEL; ++c) {
                const float v = rv[c];
                const int idx = ri[c];
                if (idx < 0) continue;
                const bool lt_prev = (v < pv) || (v == pv && idx > pi);
                if (lt_prev && (v > best || (v == best && idx < bidx))) {
                    best = v;
                    bidx = idx;
                }
            }
            bw[s] = best;
            bi[s] = bidx;
            pv = best;
            pi = bidx;
        }
        // softmax over the 5 kept logits (others underflow to exact 0)
        float e[KSEL];
        float sum = 0.f;
#pragma unroll
        for (int s = 0; s < KSEL; ++s) {
            e[s] = expf((bw[s] - bw[0]) * TEMP_INV);
            sum += e[s];
        }
        const float inv = 1.0f / sum;
        const int row = i0 + r;
#pragma unroll
        for (int s = 0; s < KSEL; ++s) {
            topW[row * KSEL + s] = e[s] * inv;
            topI[row * KSEL + s] = bi[s];
        }
    }
}

// ---------------- Kernel 3: zero-fill output -----------------------------
__global__ __launch_bounds__(256) void zero_kernel(float4* __restrict__ out, long n4) {
    long i = (long)blockIdx.x * blockDim.x + threadIdx.x;
    const long stride = (long)gridDim.x * blockDim.x;
    const float4 z = make_float4(0.f, 0.f, 0.f, 0.f);
    for (; i < n4; i += stride) out[i] = z;
}

// ---------------- Kernel 4: scatter top-5 weights ------------------------
__global__ __launch_bounds__(256) void scatter_kernel(const float* __restrict__ topW,
                                                      const int* __restrict__ topI,
                                                      float* __restrict__ out) {
    const int t = blockIdx.x * blockDim.x + threadIdx.x;
    if (t < N * KSEL) {
        const int row = t / KSEL;
        const int col = topI[t];
        out[(size_t)row * N + col] = topW[t];
    }
}

extern "C" void kernel_launch(void* const* d_in, const int* in_sizes, int n_in,
                              void* d_out, int out_size, void* d_ws, size_t ws_size,
                              hipStream_t stream) {
    const float* X = (const float*)d_in[0];
    float* out = (float*)d_out;
    // workspace layout: Xn [N*D f32 = 16 MB] | topW [N*5 f32] | topI [N*5 i32]
    float* Xn = (float*)d_ws;
    float* topW = Xn + (size_t)N * D;
    int* topI = (int*)(topW + (size_t)N * KSEL);

    const long n4 = ((long)N * N) / 4;
    hipLaunchKernelGGL(zero_kernel, dim3(2048), dim3(256), 0, stream, (float4*)out, n4);
    hipLaunchKernelGGL(rownorm_kernel, dim3(N), dim3(64), 0, stream, X, Xn);
    hipLaunchKernelGGL(simtopk_kernel, dim3(N / TI), dim3(BLK), 0, stream, Xn, topW, topI);
    hipLaunchKernelGGL(scatter_kernel, dim3((N * KSEL + 255) / 256), dim3(256), 0, stream,
                       topW, topI, out);
}

// Round 2
// 1872.589 us; speedup vs baseline: 7.7746x; 7.7746x over previous
//
#include <hip/hip_runtime.h>
#include <math.h>

#define N 8192
#define D 512
#define KSEL 5
#define TI 32           // i-rows per block (4 per wave)
#define TJ 256          // j-cols per tile (4 per lane)
#define BK 32           // k-chunk
#define NJQ 2           // j-split (halves) -> 512 blocks
#define JSPAN (N / NJQ) // 4096
#define TEMP_INV 10.0f

// Lexicographic top-5 insert: (value desc, index asc) — matches lax.top_k
// tie-break. All indices compile-time (full unroll) so arrays stay in VGPRs.
#define INS(TV, TIX, RI, VV, JJ)                                                     \
  {                                                                                  \
    const float _v = (VV);                                                           \
    const int _j = (JJ);                                                             \
    const bool _b4 = (_v > TV[RI][4]) || (_v == TV[RI][4] && _j < TIX[RI][4]);       \
    if (_b4) {                                                                       \
      const bool _b0 = (_v > TV[RI][0]) || (_v == TV[RI][0] && _j < TIX[RI][0]);     \
      const bool _b1 = (_v > TV[RI][1]) || (_v == TV[RI][1] && _j < TIX[RI][1]);     \
      const bool _b2 = (_v > TV[RI][2]) || (_v == TV[RI][2] && _j < TIX[RI][2]);     \
      const bool _b3 = (_v > TV[RI][3]) || (_v == TV[RI][3] && _j < TIX[RI][3]);     \
      TV[RI][4] = _b3 ? TV[RI][3] : _v;                                              \
      TIX[RI][4] = _b3 ? TIX[RI][3] : _j;                                            \
      TV[RI][3] = _b2 ? TV[RI][2] : (_b3 ? _v : TV[RI][3]);                          \
      TIX[RI][3] = _b2 ? TIX[RI][2] : (_b3 ? _j : TIX[RI][3]);                       \
      TV[RI][2] = _b1 ? TV[RI][1] : (_b2 ? _v : TV[RI][2]);                          \
      TIX[RI][2] = _b1 ? TIX[RI][1] : (_b2 ? _j : TIX[RI][2]);                       \
      TV[RI][1] = _b0 ? TV[RI][0] : (_b1 ? _v : TV[RI][1]);                          \
      TIX[RI][1] = _b0 ? TIX[RI][0] : (_b1 ? _j : TIX[RI][1]);                       \
      TV[RI][0] = _b0 ? _v : TV[RI][0];                                              \
      TIX[RI][0] = _b0 ? _j : TIX[RI][0];                                            \
    }                                                                                \
  }

// ---------------- Kernel 1: row inverse-norms ----------------------------
__global__ __launch_bounds__(64) void norm_kernel(const float* __restrict__ X,
                                                  float* __restrict__ inv) {
    const int row = blockIdx.x;
    const int t = threadIdx.x;
    const float4* xr = (const float4*)(X + (size_t)row * D);
    const float4 a = xr[t];
    const float4 b = xr[t + 64];
    float ss = a.x * a.x + a.y * a.y + a.z * a.z + a.w * a.w +
               b.x * b.x + b.y * b.y + b.z * b.z + b.w * b.w;
#pragma unroll
    for (int off = 32; off > 0; off >>= 1) ss += __shfl_xor(ss, off, 64);
    if (t == 0) inv[row] = 1.0f / fmaxf(sqrtf(ss), 1e-12f);
}

// ---------------- Kernel 2: normalize + transpose to k-major -------------
// XnT[k][j] = X[j][k] * inv[j], 64x64 tiles through LDS.
__global__ __launch_bounds__(256) void transpose_kernel(const float* __restrict__ X,
                                                        const float* __restrict__ inv,
                                                        float* __restrict__ XnT) {
    __shared__ float tile[64][68];  // pad 4 keeps float4 alignment (68*4=272=17*16)
    const int t = threadIdx.x;
    const int j0 = ((int)blockIdx.x & 127) * 64;
    const int k0 = ((int)blockIdx.x >> 7) * 64;
    const int lr = t >> 4;   // 0..15
    const int lc = t & 15;   // 0..15
#pragma unroll
    for (int p = 0; p < 4; ++p) {
        const int jl = p * 16 + lr;
        const float s = inv[j0 + jl];
        const float4 v = *(const float4*)&X[(size_t)(j0 + jl) * D + k0 + lc * 4];
        *(float4*)&tile[jl][lc * 4] = make_float4(v.x * s, v.y * s, v.z * s, v.w * s);
    }
    __syncthreads();
#pragma unroll
    for (int p = 0; p < 4; ++p) {
        const int kl = p * 16 + lr;
        float4 o;
        o.x = tile[lc * 4 + 0][kl];
        o.y = tile[lc * 4 + 1][kl];
        o.z = tile[lc * 4 + 2][kl];
        o.w = tile[lc * 4 + 3][kl];
        *(float4*)&XnT[(size_t)(k0 + kl) * N + j0 + lc * 4] = o;
    }
}

// ---------------- Kernel 3: fused sim + top-5 (the hot kernel) -----------
// 512 threads = 8 waves. Wave w owns rows i0+4w..i0+4w+3 (A-frag is
// wave-uniform -> LDS broadcast, free). Lane owns 4 consecutive j.
// LDS k-major tiles, lane-contiguous b128 reads: conflict-free.
__global__ __launch_bounds__(512, 4) void simtopk_kernel(const float* __restrict__ XnT,
                                                         float* __restrict__ qv,
                                                         int* __restrict__ qi) {
    __shared__ float As[BK * TI];  // 4 KB  [k][r]
    __shared__ float Bs[BK * TJ];  // 32 KB [k][j]
    const int tid = threadIdx.x;
    const int w = tid >> 6;
    const int lane = tid & 63;
    const int it = (int)blockIdx.x >> 1;
    const int jq = (int)blockIdx.x & 1;
    const int i0 = it * TI;
    const int jorg = jq * JSPAN;

    float tv[4][5];
    int tix[4][5];
#pragma unroll
    for (int r = 0; r < 4; ++r)
#pragma unroll
        for (int s = 0; s < 5; ++s) {
            tv[r][s] = -1e30f;
            tix[r][s] = 0x7fffffff;
        }

    // staging indices
    const int akk = tid >> 4;         // 0..31 (k-row for A stage)
    const int ace = (tid & 15) * 2;   // 0..30 (col pair)
    const float* apBase = As + w * 4;
    const float* bpBase = Bs + lane * 4;

    for (int jt = 0; jt < JSPAN / TJ; ++jt) {
        const int jbase = jorg + jt * TJ;
        float acc[4][4];
#pragma unroll
        for (int r = 0; r < 4; ++r)
#pragma unroll
            for (int c = 0; c < 4; ++c) acc[r][c] = 0.0f;

        // prefetch chunk 0 into registers
        float4 breg[4];
        float2 areg;
#pragma unroll
        for (int p = 0; p < 4; ++p) {
            const int idx = p * 512 + tid;
            breg[p] = *(const float4*)&XnT[(size_t)(idx >> 6) * N + jbase + (idx & 63) * 4];
        }
        areg = *(const float2*)&XnT[(size_t)akk * N + i0 + ace];

        for (int kc = 0; kc < D / BK; ++kc) {
            __syncthreads();  // previous chunk's readers done
#pragma unroll
            for (int p = 0; p < 4; ++p) {
                const int idx = p * 512 + tid;
                *(float4*)&Bs[(idx >> 6) * TJ + (idx & 63) * 4] = breg[p];
            }
            *(float2*)&As[akk * TI + ace] = areg;
            __syncthreads();
            // prefetch next chunk (global latency hides under compute)
            if (kc < D / BK - 1) {
                const int k0n = (kc + 1) * BK;
#pragma unroll
                for (int p = 0; p < 4; ++p) {
                    const int idx = p * 512 + tid;
                    breg[p] = *(const float4*)&XnT[(size_t)(k0n + (idx >> 6)) * N + jbase +
                                                   (idx & 63) * 4];
                }
                areg = *(const float2*)&XnT[(size_t)(k0n + akk) * N + i0 + ace];
            }
#pragma unroll
            for (int k = 0; k < BK; ++k) {
                const float4 av = *(const float4*)(apBase + k * TI);
                const float4 bv = *(const float4*)(bpBase + k * TJ);
                acc[0][0] += av.x * bv.x; acc[0][1] += av.x * bv.y;
                acc[0][2] += av.x * bv.z; acc[0][3] += av.x * bv.w;
                acc[1][0] += av.y * bv.x; acc[1][1] += av.y * bv.y;
                acc[1][2] += av.y * bv.z; acc[1][3] += av.y * bv.w;
                acc[2][0] += av.z * bv.x; acc[2][1] += av.z * bv.y;
                acc[2][2] += av.z * bv.z; acc[2][3] += av.z * bv.w;
                acc[3][0] += av.w * bv.x; acc[3][1] += av.w * bv.y;
                acc[3][2] += av.w * bv.z; acc[3][3] += av.w * bv.w;
            }
        }
        // fold this j-tile into per-lane top-5 (ascending j within thread)
        const int jb = jbase + lane * 4;
#pragma unroll
        for (int r = 0; r < 4; ++r) {
            INS(tv, tix, r, acc[r][0], jb + 0);
            INS(tv, tix, r, acc[r][1], jb + 1);
            INS(tv, tix, r, acc[r][2], jb + 2);
            INS(tv, tix, r, acc[r][3], jb + 3);
        }
    }

    // wave butterfly merge: snapshot partner's 5 BEFORE inserting (lock-step)
#pragma unroll
    for (int m = 1; m < 64; m <<= 1) {
#pragma unroll
        for (int r = 0; r < 4; ++r) {
            float pv0 = __shfl_xor(tv[r][0], m, 64);
            float pv1 = __shfl_xor(tv[r][1], m, 64);
            float pv2 = __shfl_xor(tv[r][2], m, 64);
            float pv3 = __shfl_xor(tv[r][3], m, 64);
            float pv4 = __shfl_xor(tv[r][4], m, 64);
            int pi0 = __shfl_xor(tix[r][0], m, 64);
            int pi1 = __shfl_xor(tix[r][1], m, 64);
            int pi2 = __shfl_xor(tix[r][2], m, 64);
            int pi3 = __shfl_xor(tix[r][3], m, 64);
            int pi4 = __shfl_xor(tix[r][4], m, 64);
            INS(tv, tix, r, pv0, pi0);
            INS(tv, tix, r, pv1, pi1);
            INS(tv, tix, r, pv2, pi2);
            INS(tv, tix, r, pv3, pi3);
            INS(tv, tix, r, pv4, pi4);
        }
    }

    if (lane == 0) {
#pragma unroll
        for (int r = 0; r < 4; ++r) {
            const int row = i0 + w * 4 + r;
            float* dv = qv + (size_t)row * (NJQ * KSEL) + jq * KSEL;
            int* di = qi + (size_t)row * (NJQ * KSEL) + jq * KSEL;
            dv[0] = tv[r][0]; dv[1] = tv[r][1]; dv[2] = tv[r][2];
            dv[3] = tv[r][3]; dv[4] = tv[r][4];
            di[0] = tix[r][0]; di[1] = tix[r][1]; di[2] = tix[r][2];
            di[3] = tix[r][3]; di[4] = tix[r][4];
        }
    }
}

// ---------------- Kernel 4: zero-fill output -----------------------------
__global__ __launch_bounds__(256) void zero_kernel(float4* __restrict__ out, long n4) {
    long i = (long)blockIdx.x * blockDim.x + threadIdx.x;
    const long stride = (long)gridDim.x * blockDim.x;
    const float4 z = make_float4(0.f, 0.f, 0.f, 0.f);
    for (; i < n4; i += stride) out[i] = z;
}

// ---------------- Kernel 5: merge halves + softmax + scatter -------------
__global__ __launch_bounds__(256) void finalize_kernel(const float* __restrict__ qv,
                                                       const int* __restrict__ qi,
                                                       float* __restrict__ out) {
    const int row = blockIdx.x * 256 + threadIdx.x;
    float tv[1][5];
    int tix[1][5];
#pragma unroll
    for (int s = 0; s < 5; ++s) {
        tv[0][s] = -1e30f;
        tix[0][s] = 0x7fffffff;
    }
    const float* rv = qv + (size_t)row * (NJQ * KSEL);
    const int* ri = qi + (size_t)row * (NJQ * KSEL);
#pragma unroll
    for (int c = 0; c < NJQ * KSEL; ++c) { INS(tv, tix, 0, rv[c], ri[c]); }
    float e[KSEL];
    float sum = 0.f;
#pragma unroll
    for (int s = 0; s < KSEL; ++s) {
        e[s] = expf((tv[0][s] - tv[0][0]) * TEMP_INV);
        sum += e[s];
    }
    const float invs = 1.0f / sum;
    float* orow = out + (size_t)row * N;
#pragma unroll
    for (int s = 0; s < KSEL; ++s) orow[tix[0][s]] = e[s] * invs;
}

extern "C" void kernel_launch(void* const* d_in, const int* in_sizes, int n_in,
                              void* d_out, int out_size, void* d_ws, size_t ws_size,
                              hipStream_t stream) {
    const float* X = (const float*)d_in[0];
    float* out = (float*)d_out;
    // ws: XnT [512*8192 f32 = 16 MB] | inv [8192] | qv [8192*10] | qi [8192*10]
    float* XnT = (float*)d_ws;
    float* inv = XnT + (size_t)D * N;
    float* qv = inv + N;
    int* qi = (int*)(qv + (size_t)N * NJQ * KSEL);

    const long n4 = ((long)N * N) / 4;
    hipLaunchKernelGGL(zero_kernel, dim3(8192), dim3(256), 0, stream, (float4*)out, n4);
    hipLaunchKernelGGL(norm_kernel, dim3(N), dim3(64), 0, stream, X, inv);
    hipLaunchKernelGGL(transpose_kernel, dim3(1024), dim3(256), 0, stream, X, inv, XnT);
    hipLaunchKernelGGL(simtopk_kernel, dim3((N / TI) * NJQ), dim3(512), 0, stream, XnT, qv, qi);
    hipLaunchKernelGGL(finalize_kernel, dim3(N / 256), dim3(256), 0, stream, qv, qi, out);
}

// Round 3
// 468.223 us; speedup vs baseline: 31.0935x; 3.9994x over previous
//
#include <hip/hip_runtime.h>
#include <math.h>

#define N 8192
#define D 512
#define KSEL 5
#define TEMP_INV 10.0f
#define MARGIN 0.01f
#define MAXCAND 48
#define APAD 40  // LDS row pitch in shorts: 32 k + 8 pad = 80 B (2-way-free banks)

using short8 = __attribute__((ext_vector_type(8))) short;
using floatx4 = __attribute__((ext_vector_type(4))) float;

// Lexicographic top-5 insert: (value desc, index asc) — matches lax.top_k.
#define INS(TV, TIX, RI, VV, JJ)                                                     \
  {                                                                                  \
    const float _v = (VV);                                                           \
    const int _j = (JJ);                                                             \
    const bool _b4 = (_v > TV[RI][4]) || (_v == TV[RI][4] && _j < TIX[RI][4]);       \
    if (_b4) {                                                                       \
      const bool _b0 = (_v > TV[RI][0]) || (_v == TV[RI][0] && _j < TIX[RI][0]);     \
      const bool _b1 = (_v > TV[RI][1]) || (_v == TV[RI][1] && _j < TIX[RI][1]);     \
      const bool _b2 = (_v > TV[RI][2]) || (_v == TV[RI][2] && _j < TIX[RI][2]);     \
      const bool _b3 = (_v > TV[RI][3]) || (_v == TV[RI][3] && _j < TIX[RI][3]);     \
      TV[RI][4] = _b3 ? TV[RI][3] : _v;                                              \
      TIX[RI][4] = _b3 ? TIX[RI][3] : _j;                                            \
      TV[RI][3] = _b2 ? TV[RI][2] : (_b3 ? _v : TV[RI][3]);                          \
      TIX[RI][3] = _b2 ? TIX[RI][2] : (_b3 ? _j : TIX[RI][3]);                       \
      TV[RI][2] = _b1 ? TV[RI][1] : (_b2 ? _v : TV[RI][2]);                          \
      TIX[RI][2] = _b1 ? TIX[RI][1] : (_b2 ? _j : TIX[RI][2]);                       \
      TV[RI][1] = _b0 ? TV[RI][0] : (_b1 ? _v : TV[RI][1]);                          \
      TIX[RI][1] = _b0 ? TIX[RI][0] : (_b1 ? _j : TIX[RI][1]);                       \
      TV[RI][0] = _b0 ? _v : TV[RI][0];                                              \
      TIX[RI][0] = _b0 ? _j : TIX[RI][0];                                            \
    }                                                                                \
  }

__device__ inline unsigned short f2b(float f) {  // fp32 -> bf16 RNE
    unsigned int u = __float_as_uint(f);
    unsigned int r = (u + 0x7FFFu + ((u >> 16) & 1u)) >> 16;
    return (unsigned short)r;
}

// ---------------- Kernel 1: norms + bf16 normalized rows -----------------
__global__ __launch_bounds__(64) void prep_kernel(const float* __restrict__ X,
                                                  unsigned short* __restrict__ Xb,
                                                  float* __restrict__ inv) {
    const int row = blockIdx.x;
    const int t = threadIdx.x;
    const float4* xr = (const float4*)(X + (size_t)row * D);
    const float4 a = xr[t];
    const float4 b = xr[t + 64];
    float ss = a.x * a.x + a.y * a.y + a.z * a.z + a.w * a.w +
               b.x * b.x + b.y * b.y + b.z * b.z + b.w * b.w;
#pragma unroll
    for (int off = 32; off > 0; off >>= 1) ss += __shfl_xor(ss, off, 64);
    const float iv = 1.0f / fmaxf(sqrtf(ss), 1e-12f);
    if (t == 0) inv[row] = iv;
    ushort4 ua, ub;
    ua.x = f2b(a.x * iv); ua.y = f2b(a.y * iv); ua.z = f2b(a.z * iv); ua.w = f2b(a.w * iv);
    ub.x = f2b(b.x * iv); ub.y = f2b(b.y * iv); ub.z = f2b(b.z * iv); ub.w = f2b(b.w * iv);
    ((ushort4*)(Xb + (size_t)row * D))[t] = ua;
    ((ushort4*)(Xb + (size_t)row * D))[t + 64] = ub;
}

// ---------------- Kernel 2: bf16 MFMA GEMM, sim -> d_out (scratch) -------
// 128x128 tile, 256 thr = 4 waves in 2x2; wave owns 64x64 = 4x4 MFMA tiles.
// A-frag: A[m=lane&15][k=(lane>>4)*8+j]; B-frag: B[k][n=lane&15] symmetric.
__global__ __launch_bounds__(256) void gemm_kernel(const unsigned short* __restrict__ Xb,
                                                   float* __restrict__ simout) {
    __shared__ unsigned short Al[128 * APAD];  // 10 KB
    __shared__ unsigned short Bl[128 * APAD];
    const int tid = threadIdx.x;
    const int w = tid >> 6;
    const int lane = tid & 63;
    const int wr = w >> 1, wc = w & 1;
    const int i0 = blockIdx.y * 128, j0 = blockIdx.x * 128;

    const int r0 = tid >> 2;  // 0..63 staging row
    const int q = tid & 3;    // 16B chunk within row

    floatx4 acc[4][4];
#pragma unroll
    for (int ti = 0; ti < 4; ++ti)
#pragma unroll
        for (int tj = 0; tj < 4; ++tj) acc[ti][tj] = (floatx4){0.f, 0.f, 0.f, 0.f};

    const unsigned short* gA0 = Xb + (size_t)(i0 + r0) * D + q * 8;
    const unsigned short* gA1 = Xb + (size_t)(i0 + r0 + 64) * D + q * 8;
    const unsigned short* gB0 = Xb + (size_t)(j0 + r0) * D + q * 8;
    const unsigned short* gB1 = Xb + (size_t)(j0 + r0 + 64) * D + q * 8;

    int4 pa0 = *(const int4*)gA0;
    int4 pa1 = *(const int4*)gA1;
    int4 pb0 = *(const int4*)gB0;
    int4 pb1 = *(const int4*)gB1;

    const int lrow = lane & 15;
    const int lq = lane >> 4;
    const unsigned short* aF = Al + (size_t)(wr * 64 + lrow) * APAD + lq * 8;
    const unsigned short* bF = Bl + (size_t)(wc * 64 + lrow) * APAD + lq * 8;

    for (int kc = 0; kc < D / 32; ++kc) {
        __syncthreads();
        *(int4*)&Al[r0 * APAD + q * 8] = pa0;
        *(int4*)&Al[(r0 + 64) * APAD + q * 8] = pa1;
        *(int4*)&Bl[r0 * APAD + q * 8] = pb0;
        *(int4*)&Bl[(r0 + 64) * APAD + q * 8] = pb1;
        __syncthreads();
        if (kc < D / 32 - 1) {
            const int o = (kc + 1) * 32;
            pa0 = *(const int4*)(gA0 + o);
            pa1 = *(const int4*)(gA1 + o);
            pb0 = *(const int4*)(gB0 + o);
            pb1 = *(const int4*)(gB1 + o);
        }
        short8 af[4], bf[4];
#pragma unroll
        for (int ti = 0; ti < 4; ++ti) af[ti] = *(const short8*)(aF + ti * 16 * APAD);
#pragma unroll
        for (int tj = 0; tj < 4; ++tj) bf[tj] = *(const short8*)(bF + tj * 16 * APAD);
#pragma unroll
        for (int ti = 0; ti < 4; ++ti)
#pragma unroll
            for (int tj = 0; tj < 4; ++tj)
                acc[ti][tj] = __builtin_amdgcn_mfma_f32_16x16x32_bf16(af[ti], bf[tj],
                                                                      acc[ti][tj], 0, 0, 0);
    }

    // C/D: col = lane&15, row = (lane>>4)*4 + reg  [m89-verified]
    const int orow0 = i0 + wr * 64 + lq * 4;
    const int ocol0 = j0 + wc * 64 + lrow;
#pragma unroll
    for (int ti = 0; ti < 4; ++ti)
#pragma unroll
        for (int tj = 0; tj < 4; ++tj)
#pragma unroll
            for (int reg = 0; reg < 4; ++reg)
                simout[(size_t)(orow0 + ti * 16 + reg) * N + ocol0 + tj * 16] =
                    acc[ti][tj][reg];
}

// ---------------- Kernel 3: scan approx sim, rescore in fp32 -------------
__global__ __launch_bounds__(256) void topkscan_kernel(const float* __restrict__ sim,
                                                       const float* __restrict__ X,
                                                       const float* __restrict__ inv,
                                                       float* __restrict__ qv,
                                                       int* __restrict__ qi) {
    __shared__ float scv[4][MAXCAND];
    __shared__ int sci[4][MAXCAND];
    __shared__ int scnt[4];
    const int tid = threadIdx.x;
    const int w = tid >> 6;
    const int lane = tid & 63;
    const int row = blockIdx.x * 4 + w;
    if (tid < 4) scnt[tid] = 0;
    __syncthreads();

    float lv[1][5];
    int li[1][5];
#pragma unroll
    for (int s = 0; s < 5; ++s) { lv[0][s] = -1e30f; li[0][s] = 0x7fffffff; }

    const float4* srow = (const float4*)(sim + (size_t)row * N);
    for (int it = 0; it < 32; ++it) {
        const float4 v = srow[it * 64 + lane];
        const int jb = it * 256 + lane * 4;
        INS(lv, li, 0, v.x, jb);
        INS(lv, li, 0, v.y, jb + 1);
        INS(lv, li, 0, v.z, jb + 2);
        INS(lv, li, 0, v.w, jb + 3);
    }

    // butterfly merge copy -> approx global 5th
    float mv[1][5];
    int mi[1][5];
#pragma unroll
    for (int s = 0; s < 5; ++s) { mv[0][s] = lv[0][s]; mi[0][s] = li[0][s]; }
#pragma unroll
    for (int m = 1; m < 64; m <<= 1) {
        float p0 = __shfl_xor(mv[0][0], m, 64), p1 = __shfl_xor(mv[0][1], m, 64);
        float p2 = __shfl_xor(mv[0][2], m, 64), p3 = __shfl_xor(mv[0][3], m, 64);
        float p4 = __shfl_xor(mv[0][4], m, 64);
        int q0 = __shfl_xor(mi[0][0], m, 64), q1 = __shfl_xor(mi[0][1], m, 64);
        int q2 = __shfl_xor(mi[0][2], m, 64), q3 = __shfl_xor(mi[0][3], m, 64);
        int q4 = __shfl_xor(mi[0][4], m, 64);
        INS(mv, mi, 0, p0, q0);
        INS(mv, mi, 0, p1, q1);
        INS(mv, mi, 0, p2, q2);
        INS(mv, mi, 0, p3, q3);
        INS(mv, mi, 0, p4, q4);
    }
    const float T = mv[0][4] - MARGIN;

    // compact candidates (per-lane top-5 entries >= T)
#pragma unroll
    for (int s = 0; s < 5; ++s) {
        if (lv[0][s] >= T) {
            const int p = atomicAdd(&scnt[w], 1);
            if (p < MAXCAND) { scv[w][p] = lv[0][s]; sci[w][p] = li[0][s]; }
        }
    }
    __syncthreads();
    int nc = scnt[w];
    if (nc > MAXCAND) nc = MAXCAND;

    // fp32 rescore: dot(X[row],X[c]) * inv_row * inv_c, wave-cooperative
    const float4* xr = (const float4*)(X + (size_t)row * D);
    const float4 xa = xr[lane * 2];
    const float4 xb = xr[lane * 2 + 1];
    const float myinv = inv[row];
    float ev[1][5];
    int ei[1][5];
#pragma unroll
    for (int s = 0; s < 5; ++s) { ev[0][s] = -1e30f; ei[0][s] = 0x7fffffff; }
    for (int c = 0; c < nc; ++c) {
        const int cj = sci[w][c];
        const float4* yr = (const float4*)(X + (size_t)cj * D);
        const float4 ya = yr[lane * 2];
        const float4 yb = yr[lane * 2 + 1];
        float p = xa.x * ya.x + xa.y * ya.y + xa.z * ya.z + xa.w * ya.w +
                  xb.x * yb.x + xb.y * yb.y + xb.z * yb.z + xb.w * yb.w;
#pragma unroll
        for (int off = 32; off > 0; off >>= 1) p += __shfl_xor(p, off, 64);
        const float val = p * myinv * inv[cj];
        INS(ev, ei, 0, val, cj);  // uniform across lanes
    }

    if (lane == 0) {
        float e[KSEL];
        float sum = 0.f;
#pragma unroll
        for (int s = 0; s < KSEL; ++s) {
            e[s] = expf((ev[0][s] - ev[0][0]) * TEMP_INV);
            sum += e[s];
        }
        const float invs = 1.0f / sum;
#pragma unroll
        for (int s = 0; s < KSEL; ++s) {
            qv[(size_t)row * KSEL + s] = e[s] * invs;
            qi[(size_t)row * KSEL + s] = ei[0][s];
        }
    }
}

// ---------------- Kernel 4: zero-fill output -----------------------------
__global__ __launch_bounds__(256) void zero_kernel(float4* __restrict__ out, long n4) {
    long i = (long)blockIdx.x * blockDim.x + threadIdx.x;
    const long stride = (long)gridDim.x * blockDim.x;
    const float4 z = make_float4(0.f, 0.f, 0.f, 0.f);
    for (; i < n4; i += stride) out[i] = z;
}

// ---------------- Kernel 5: scatter --------------------------------------
__global__ __launch_bounds__(256) void scatter_kernel(const float* __restrict__ qv,
                                                      const int* __restrict__ qi,
                                                      float* __restrict__ out) {
    const int t = blockIdx.x * blockDim.x + threadIdx.x;
    if (t < N * KSEL) {
        const int row = t / KSEL;
        out[(size_t)row * N + qi[t]] = qv[t];
    }
}

extern "C" void kernel_launch(void* const* d_in, const int* in_sizes, int n_in,
                              void* d_out, int out_size, void* d_ws, size_t ws_size,
                              hipStream_t stream) {
    const float* X = (const float*)d_in[0];
    float* out = (float*)d_out;
    // ws: Xb bf16 [N*D = 8 MB] | inv [N f32] | qv [N*5 f32] | qi [N*5 i32]
    unsigned short* Xb = (unsigned short*)d_ws;
    float* inv = (float*)(Xb + (size_t)N * D);
    float* qv = inv + N;
    int* qi = (int*)(qv + (size_t)N * KSEL);

    hipLaunchKernelGGL(prep_kernel, dim3(N), dim3(64), 0, stream, X, Xb, inv);
    // d_out doubles as 256 MB scratch for the approximate sim matrix
    hipLaunchKernelGGL(gemm_kernel, dim3(N / 128, N / 128), dim3(256), 0, stream, Xb, out);
    hipLaunchKernelGGL(topkscan_kernel, dim3(N / 4), dim3(256), 0, stream, out, X, inv, qv, qi);
    const long n4 = ((long)N * N) / 4;
    hipLaunchKernelGGL(zero_kernel, dim3(8192), dim3(256), 0, stream, (float4*)out, n4);
    hipLaunchKernelGGL(scatter_kernel, dim3((N * KSEL + 255) / 256), dim3(256), 0, stream,
                       qv, qi, out);
}